// Round 2
// baseline (1557.971 us; speedup 1.0000x reference)
//
#include <hip/hip_runtime.h>
#include <hip/hip_bf16.h>

#define NN 100000
#define NE 1600000
#define DD 64

// ---------------- K1: support[N,64] = x[N,64] @ W[64,64] (all f32) ----------------
// One wave computes 4 rows; lane = output column. W staged in LDS.
__global__ __launch_bounds__(256) void k_gemm(const float* __restrict__ x,
                                              const float* __restrict__ Wg,
                                              float* __restrict__ support) {
    __shared__ float Ws[DD * DD];
    for (int i = threadIdx.x; i < DD * DD; i += 256)
        Ws[i] = Wg[i];
    __syncthreads();

    const int wave = threadIdx.x >> 6, lane = threadIdx.x & 63;
    const size_t row0 = (size_t)blockIdx.x * 16 + (size_t)wave * 4;   // grid covers exactly 100000 rows
    const float* xr = x + row0 * DD;

    float acc0 = 0.f, acc1 = 0.f, acc2 = 0.f, acc3 = 0.f;
#pragma unroll
    for (int k = 0; k < DD; k += 4) {
        float4 p0 = *(const float4*)(xr + 0 * DD + k);
        float4 p1 = *(const float4*)(xr + 1 * DD + k);
        float4 p2 = *(const float4*)(xr + 2 * DD + k);
        float4 p3 = *(const float4*)(xr + 3 * DD + k);
        float w0 = Ws[(k + 0) * DD + lane];
        float w1 = Ws[(k + 1) * DD + lane];
        float w2 = Ws[(k + 2) * DD + lane];
        float w3 = Ws[(k + 3) * DD + lane];
        acc0 = fmaf(p0.x, w0, acc0); acc0 = fmaf(p0.y, w1, acc0);
        acc0 = fmaf(p0.z, w2, acc0); acc0 = fmaf(p0.w, w3, acc0);
        acc1 = fmaf(p1.x, w0, acc1); acc1 = fmaf(p1.y, w1, acc1);
        acc1 = fmaf(p1.z, w2, acc1); acc1 = fmaf(p1.w, w3, acc1);
        acc2 = fmaf(p2.x, w0, acc2); acc2 = fmaf(p2.y, w1, acc2);
        acc2 = fmaf(p2.z, w2, acc2); acc2 = fmaf(p2.w, w3, acc2);
        acc3 = fmaf(p3.x, w0, acc3); acc3 = fmaf(p3.y, w1, acc3);
        acc3 = fmaf(p3.z, w2, acc3); acc3 = fmaf(p3.w, w3, acc3);
    }
    float* sp = support + row0 * DD + lane;
    sp[0 * DD] = acc0; sp[1 * DD] = acc1; sp[2 * DD] = acc2; sp[3 * DD] = acc3;
}

// ---------------- K2: scatter-add  agg[dst] += w * support[src] ----------------
// 16 lanes per edge, float4 per lane (4 feats), 4 f32 atomics per lane.
__global__ __launch_bounds__(256) void k_scatter(const int* __restrict__ src,
                                                 const int* __restrict__ dst,
                                                 const float* __restrict__ ew,
                                                 const float* __restrict__ support,
                                                 float* __restrict__ agg) {
    const int t = blockIdx.x * 256 + threadIdx.x;   // grid covers exactly NE*16 threads
    const int e = t >> 4;
    const int q = (t & 15) * 4;
    const int s = src[e], d = dst[e];
    const float w = ew[e];
    const float4 v = *(const float4*)(support + (size_t)s * DD + q);
    float* o = agg + (size_t)d * DD + q;
    atomicAdd(o + 0, w * v.x);
    atomicAdd(o + 1, w * v.y);
    atomicAdd(o + 2, w * v.z);
    atomicAdd(o + 3, w * v.w);
}

// ---------------- K3: per-column sum & sumsq of agg ----------------
__device__ inline float4 shfl_down4(float4 v, int d) {
    v.x = __shfl_down(v.x, d, 64); v.y = __shfl_down(v.y, d, 64);
    v.z = __shfl_down(v.z, d, 64); v.w = __shfl_down(v.w, d, 64);
    return v;
}
__device__ inline float4 add4(float4 a, float4 b) {
    a.x += b.x; a.y += b.y; a.z += b.z; a.w += b.w; return a;
}

__global__ __launch_bounds__(256) void k_stats(const float* __restrict__ agg,
                                               float* __restrict__ stats) {
    const int lane = threadIdx.x & 63, wave = threadIdx.x >> 6;
    const int q = lane & 15, sub = lane >> 4;
    float4 s = {0, 0, 0, 0}, sq = {0, 0, 0, 0};
    const int stride = gridDim.x * 16;                 // rows per grid iteration
    for (int row = (blockIdx.x * 4 + wave) * 4 + sub; row < NN; row += stride) {
        float4 v = *(const float4*)(agg + (size_t)row * DD + q * 4);
        s.x += v.x; s.y += v.y; s.z += v.z; s.w += v.w;
        sq.x = fmaf(v.x, v.x, sq.x); sq.y = fmaf(v.y, v.y, sq.y);
        sq.z = fmaf(v.z, v.z, sq.z); sq.w = fmaf(v.w, v.w, sq.w);
    }
    s = add4(s, shfl_down4(s, 32));  s = add4(s, shfl_down4(s, 16));
    sq = add4(sq, shfl_down4(sq, 32)); sq = add4(sq, shfl_down4(sq, 16));

    __shared__ float red[2][4][DD];
    if (lane < 16) {
        red[0][wave][q * 4 + 0] = s.x;  red[0][wave][q * 4 + 1] = s.y;
        red[0][wave][q * 4 + 2] = s.z;  red[0][wave][q * 4 + 3] = s.w;
        red[1][wave][q * 4 + 0] = sq.x; red[1][wave][q * 4 + 1] = sq.y;
        red[1][wave][q * 4 + 2] = sq.z; red[1][wave][q * 4 + 3] = sq.w;
    }
    __syncthreads();
    if (threadIdx.x < DD) {
        const int c = threadIdx.x;
        float ts = red[0][0][c] + red[0][1][c] + red[0][2][c] + red[0][3][c];
        float tq = red[1][0][c] + red[1][1][c] + red[1][2][c] + red[1][3][c];
        atomicAdd(&stats[c], ts);
        atomicAdd(&stats[DD + c], tq);
    }
}

// ---------------- K4: fold mean/var/gamma/beta into scale/shift ----------------
__global__ void k_finstats(const float* __restrict__ sums, float* __restrict__ ss,
                           const float* __restrict__ gamma,
                           const float* __restrict__ beta) {
    const int c = threadIdx.x;
    const float invn = 1.0f / NN;
    float mean = sums[c] * invn;
    float var = fmaxf(sums[DD + c] * invn - mean * mean, 0.f);
    float sc = rsqrtf(var + 1e-5f) * gamma[c];
    ss[c] = sc;
    ss[DD + c] = beta[c] - mean * sc;
}

// ---------------- K5: out = relu(agg*scale + shift) (f32) ----------------
__global__ __launch_bounds__(256) void k_final(const float* __restrict__ agg,
                                               const float* __restrict__ ss,
                                               float* __restrict__ out) {
    const size_t idx = ((size_t)blockIdx.x * 256 + threadIdx.x) * 4;
    const int c = (int)(idx & 63);
    float4 v = *(const float4*)(agg + idx);
    float4 o;
    o.x = fmaxf(fmaf(v.x, ss[c + 0], ss[DD + c + 0]), 0.f);
    o.y = fmaxf(fmaf(v.y, ss[c + 1], ss[DD + c + 1]), 0.f);
    o.z = fmaxf(fmaf(v.z, ss[c + 2], ss[DD + c + 2]), 0.f);
    o.w = fmaxf(fmaf(v.w, ss[c + 3], ss[DD + c + 3]), 0.f);
    *(float4*)(out + idx) = o;
}

extern "C" void kernel_launch(void* const* d_in, const int* in_sizes, int n_in,
                              void* d_out, int out_size, void* d_ws, size_t ws_size,
                              hipStream_t stream) {
    const float* x     = (const float*)d_in[0];
    const int*   esrc  = (const int*)d_in[1];
    const int*   edst  = (const int*)d_in[2];
    const float* ew    = (const float*)d_in[3];
    const float* W     = (const float*)d_in[4];
    // d_in[5] = bias: cancels exactly in batchnorm (shift-invariant) — unused.
    const float* gamma = (const float*)d_in[6];
    const float* beta  = (const float*)d_in[7];
    float*       out   = (float*)d_out;

    char* ws = (char*)d_ws;
    float* support = (float*)ws;                                 // 25.6 MB
    float* agg     = (float*)(ws + (size_t)NN * DD * 4);         // 25.6 MB
    float* stats   = (float*)(ws + 2 * (size_t)NN * DD * 4);     // 256 floats: sum|sumsq|scale|shift

    // zero agg + stats (d_ws is poisoned 0xAA before every timed call)
    hipMemsetAsync(agg, 0, (size_t)NN * DD * 4 + 1024, stream);

    k_gemm<<<NN / 16, 256, 0, stream>>>(x, W, support);
    k_scatter<<<(NE * 16) / 256, 256, 0, stream>>>(esrc, edst, ew, support, agg);
    k_stats<<<2048, 256, 0, stream>>>(agg, stats);
    k_finstats<<<1, 64, 0, stream>>>(stats, stats + 2 * DD, gamma, beta);
    k_final<<<(NN * DD / 4) / 256, 256, 0, stream>>>(agg, stats + 2 * DD, out);
}

// Round 3
// 511.892 us; speedup vs baseline: 3.0436x; 3.0436x over previous
//
#include <hip/hip_runtime.h>
#include <hip/hip_bf16.h>

#define NN 100000
#define NE 1600000
#define DD 64
#define NBLK 98   // ceil(NN / 1024)

// ---------------- K1: support[N,64] = x[N,64] @ W[64,64] (f32) ----------------
__global__ __launch_bounds__(256) void k_gemm(const float* __restrict__ x,
                                              const float* __restrict__ Wg,
                                              float* __restrict__ support) {
    __shared__ float Ws[DD * DD];
    for (int i = threadIdx.x; i < DD * DD; i += 256)
        Ws[i] = Wg[i];
    __syncthreads();

    const int wave = threadIdx.x >> 6, lane = threadIdx.x & 63;
    const size_t row0 = (size_t)blockIdx.x * 16 + (size_t)wave * 4;   // grid = NN/16 exactly
    const float* xr = x + row0 * DD;

    float acc0 = 0.f, acc1 = 0.f, acc2 = 0.f, acc3 = 0.f;
#pragma unroll
    for (int k = 0; k < DD; k += 4) {
        float4 p0 = *(const float4*)(xr + 0 * DD + k);
        float4 p1 = *(const float4*)(xr + 1 * DD + k);
        float4 p2 = *(const float4*)(xr + 2 * DD + k);
        float4 p3 = *(const float4*)(xr + 3 * DD + k);
        float w0 = Ws[(k + 0) * DD + lane];
        float w1 = Ws[(k + 1) * DD + lane];
        float w2 = Ws[(k + 2) * DD + lane];
        float w3 = Ws[(k + 3) * DD + lane];
        acc0 = fmaf(p0.x, w0, acc0); acc0 = fmaf(p0.y, w1, acc0);
        acc0 = fmaf(p0.z, w2, acc0); acc0 = fmaf(p0.w, w3, acc0);
        acc1 = fmaf(p1.x, w0, acc1); acc1 = fmaf(p1.y, w1, acc1);
        acc1 = fmaf(p1.z, w2, acc1); acc1 = fmaf(p1.w, w3, acc1);
        acc2 = fmaf(p2.x, w0, acc2); acc2 = fmaf(p2.y, w1, acc2);
        acc2 = fmaf(p2.z, w2, acc2); acc2 = fmaf(p2.w, w3, acc2);
        acc3 = fmaf(p3.x, w0, acc3); acc3 = fmaf(p3.y, w1, acc3);
        acc3 = fmaf(p3.z, w2, acc3); acc3 = fmaf(p3.w, w3, acc3);
    }
    float* sp = support + row0 * DD + lane;
    sp[0 * DD] = acc0; sp[1 * DD] = acc1; sp[2 * DD] = acc2; sp[3 * DD] = acc3;
}

// ---------------- CSR build ----------------
__global__ __launch_bounds__(256) void k_hist(const int* __restrict__ edst,
                                              int* __restrict__ cnt) {
    const int e = blockIdx.x * 256 + threadIdx.x;   // grid = NE/256 exactly
    atomicAdd(&cnt[edst[e]], 1);
}

// block sums of 1024-element chunks
__global__ __launch_bounds__(256) void k_bsum(const int* __restrict__ cnt,
                                              int* __restrict__ bsum) {
    const int base = blockIdx.x * 1024 + threadIdx.x * 4;
    int s = 0;
#pragma unroll
    for (int j = 0; j < 4; ++j) { int i = base + j; if (i < NN) s += cnt[i]; }
#pragma unroll
    for (int o = 32; o; o >>= 1) s += __shfl_down(s, o, 64);
    __shared__ int wsum[4];
    if ((threadIdx.x & 63) == 0) wsum[threadIdx.x >> 6] = s;
    __syncthreads();
    if (threadIdx.x == 0) bsum[blockIdx.x] = wsum[0] + wsum[1] + wsum[2] + wsum[3];
}

// exclusive scan of NBLK block sums (single block)
__global__ void k_bscan(const int* __restrict__ bsum, int* __restrict__ boff) {
    __shared__ int sc[128];
    const int t = threadIdx.x;
    const int v = (t < NBLK) ? bsum[t] : 0;
    sc[t] = v; __syncthreads();
    for (int o = 1; o < 128; o <<= 1) {
        int u = (t >= o) ? sc[t - o] : 0;
        __syncthreads();
        sc[t] += u;
        __syncthreads();
    }
    if (t < NBLK) boff[t] = sc[t] - v;
}

// per-chunk exclusive scan + global offset; writes offs[] and cur[]
__global__ __launch_bounds__(256) void k_scan(const int* __restrict__ cnt,
                                              const int* __restrict__ boff,
                                              int* __restrict__ offs,
                                              int* __restrict__ cur) {
    const int t = threadIdx.x;
    const int base = blockIdx.x * 1024 + t * 4;
    int c[4], ts = 0;
#pragma unroll
    for (int j = 0; j < 4; ++j) {
        int i = base + j;
        c[j] = (i < NN) ? cnt[i] : 0;
        ts += c[j];
    }
    __shared__ int sc[256];
    sc[t] = ts; __syncthreads();
    for (int o = 1; o < 256; o <<= 1) {
        int u = (t >= o) ? sc[t - o] : 0;
        __syncthreads();
        sc[t] += u;
        __syncthreads();
    }
    int run = sc[t] - ts + boff[blockIdx.x];
#pragma unroll
    for (int j = 0; j < 4; ++j) {
        int i = base + j;
        if (i < NN) { offs[i] = run; cur[i] = run; run += c[j]; }
    }
    if (blockIdx.x == 0 && t == 0) offs[NN] = NE;
}

// ticket-scatter edges into buckets
__global__ __launch_bounds__(256) void k_escat(const int* __restrict__ esrc,
                                               const int* __restrict__ edst,
                                               const float* __restrict__ ew,
                                               int* __restrict__ cur,
                                               int* __restrict__ srcs,
                                               float* __restrict__ ews) {
    const int e = blockIdx.x * 256 + threadIdx.x;   // grid = NE/256 exactly
    const int d = edst[e];
    const int p = atomicAdd(&cur[d], 1);
    srcs[p] = esrc[e];
    ews[p] = ew[e];
}

// ---------------- K2: gather  agg[d] = sum_e w_e * support[src_e] ----------------
// one wave per dst node, lane = feature column
__global__ __launch_bounds__(256) void k_gather(const int* __restrict__ offs,
                                                const int* __restrict__ srcs,
                                                const float* __restrict__ ews,
                                                const float* __restrict__ support,
                                                float* __restrict__ agg) {
    const int wave = threadIdx.x >> 6, lane = threadIdx.x & 63;
    const int d = blockIdx.x * 4 + wave;            // grid = NN/4 exactly
    int j = offs[d];
    const int e = offs[d + 1];
    float acc0 = 0.f, acc1 = 0.f;
    for (; j + 1 < e; j += 2) {
        const int s0 = srcs[j], s1 = srcs[j + 1];
        const float w0 = ews[j], w1 = ews[j + 1];
        acc0 = fmaf(w0, support[(size_t)s0 * DD + lane], acc0);
        acc1 = fmaf(w1, support[(size_t)s1 * DD + lane], acc1);
    }
    if (j < e)
        acc0 = fmaf(ews[j], support[(size_t)srcs[j] * DD + lane], acc0);
    agg[(size_t)d * DD + lane] = acc0 + acc1;
}

// ---------------- K3: per-column sum & sumsq ----------------
__device__ inline float4 shfl_down4(float4 v, int d) {
    v.x = __shfl_down(v.x, d, 64); v.y = __shfl_down(v.y, d, 64);
    v.z = __shfl_down(v.z, d, 64); v.w = __shfl_down(v.w, d, 64);
    return v;
}
__device__ inline float4 add4(float4 a, float4 b) {
    a.x += b.x; a.y += b.y; a.z += b.z; a.w += b.w; return a;
}

__global__ __launch_bounds__(256) void k_stats(const float* __restrict__ agg,
                                               float* __restrict__ stats) {
    const int lane = threadIdx.x & 63, wave = threadIdx.x >> 6;
    const int q = lane & 15, sub = lane >> 4;
    float4 s = {0, 0, 0, 0}, sq = {0, 0, 0, 0};
    const int stride = gridDim.x * 16;
    for (int row = (blockIdx.x * 4 + wave) * 4 + sub; row < NN; row += stride) {
        float4 v = *(const float4*)(agg + (size_t)row * DD + q * 4);
        s.x += v.x; s.y += v.y; s.z += v.z; s.w += v.w;
        sq.x = fmaf(v.x, v.x, sq.x); sq.y = fmaf(v.y, v.y, sq.y);
        sq.z = fmaf(v.z, v.z, sq.z); sq.w = fmaf(v.w, v.w, sq.w);
    }
    s = add4(s, shfl_down4(s, 32));  s = add4(s, shfl_down4(s, 16));
    sq = add4(sq, shfl_down4(sq, 32)); sq = add4(sq, shfl_down4(sq, 16));

    __shared__ float red[2][4][DD];
    if (lane < 16) {
        red[0][wave][q * 4 + 0] = s.x;  red[0][wave][q * 4 + 1] = s.y;
        red[0][wave][q * 4 + 2] = s.z;  red[0][wave][q * 4 + 3] = s.w;
        red[1][wave][q * 4 + 0] = sq.x; red[1][wave][q * 4 + 1] = sq.y;
        red[1][wave][q * 4 + 2] = sq.z; red[1][wave][q * 4 + 3] = sq.w;
    }
    __syncthreads();
    if (threadIdx.x < DD) {
        const int c = threadIdx.x;
        atomicAdd(&stats[c],      red[0][0][c] + red[0][1][c] + red[0][2][c] + red[0][3][c]);
        atomicAdd(&stats[DD + c], red[1][0][c] + red[1][1][c] + red[1][2][c] + red[1][3][c]);
    }
}

// ---------------- K4: fold stats into scale/shift ----------------
__global__ void k_finstats(const float* __restrict__ sums, float* __restrict__ ss,
                           const float* __restrict__ gamma,
                           const float* __restrict__ beta) {
    const int c = threadIdx.x;
    const float invn = 1.0f / NN;
    float mean = sums[c] * invn;
    float var = fmaxf(sums[DD + c] * invn - mean * mean, 0.f);
    float sc = rsqrtf(var + 1e-5f) * gamma[c];
    ss[c] = sc;
    ss[DD + c] = beta[c] - mean * sc;
}

// ---------------- K5: out = relu(out*scale + shift) in-place ----------------
__global__ __launch_bounds__(256) void k_final(float* __restrict__ out,
                                               const float* __restrict__ ss) {
    const size_t idx = ((size_t)blockIdx.x * 256 + threadIdx.x) * 4;
    const int c = (int)(idx & 63);
    float4 v = *(const float4*)(out + idx);
    float4 o;
    o.x = fmaxf(fmaf(v.x, ss[c + 0], ss[DD + c + 0]), 0.f);
    o.y = fmaxf(fmaf(v.y, ss[c + 1], ss[DD + c + 1]), 0.f);
    o.z = fmaxf(fmaf(v.z, ss[c + 2], ss[DD + c + 2]), 0.f);
    o.w = fmaxf(fmaf(v.w, ss[c + 3], ss[DD + c + 3]), 0.f);
    *(float4*)(out + idx) = o;
}

extern "C" void kernel_launch(void* const* d_in, const int* in_sizes, int n_in,
                              void* d_out, int out_size, void* d_ws, size_t ws_size,
                              hipStream_t stream) {
    const float* x     = (const float*)d_in[0];
    const int*   esrc  = (const int*)d_in[1];
    const int*   edst  = (const int*)d_in[2];
    const float* ew    = (const float*)d_in[3];
    const float* W     = (const float*)d_in[4];
    // d_in[5] = bias: cancels exactly in batchnorm (shift-invariant) — unused.
    const float* gamma = (const float*)d_in[6];
    const float* beta  = (const float*)d_in[7];
    float*       out   = (float*)d_out;   // reused as the agg buffer

    // workspace layout (~39.6 MB, under proven 51.2 MB budget)
    char* ws = (char*)d_ws;
    float* support = (float*)ws;                          ws += (size_t)NN * DD * 4;  // 25.6 MB
    int*   srcs    = (int*)ws;                            ws += (size_t)NE * 4;       // 6.4 MB
    float* ews     = (float*)ws;                          ws += (size_t)NE * 4;       // 6.4 MB
    int*   offs    = (int*)ws;                            ws += (NN + 4) * 4;         // 400 KB
    int*   cur     = (int*)ws;                            ws += NN * 4;               // 400 KB
    int*   cnt     = (int*)ws;                            ws += NN * 4;               // 400 KB
    float* stats   = (float*)ws;                          ws += 256 * 4;              // sum|sumsq|scale|shift
    int*   bsum    = (int*)ws;                            ws += NBLK * 4;
    int*   boff    = (int*)ws;

    // zero cnt + stats (adjacent)
    hipMemsetAsync(cnt, 0, (size_t)NN * 4 + 256 * 4, stream);

    k_gemm   <<<NN / 16, 256, 0, stream>>>(x, W, support);
    k_hist   <<<NE / 256, 256, 0, stream>>>(edst, cnt);
    k_bsum   <<<NBLK, 256, 0, stream>>>(cnt, bsum);
    k_bscan  <<<1, 128, 0, stream>>>(bsum, boff);
    k_scan   <<<NBLK, 256, 0, stream>>>(cnt, boff, offs, cur);
    k_escat  <<<NE / 256, 256, 0, stream>>>(esrc, edst, ew, cur, srcs, ews);
    k_gather <<<NN / 4, 256, 0, stream>>>(offs, srcs, ews, support, out);
    k_stats  <<<2048, 256, 0, stream>>>(out, stats);
    k_finstats<<<1, 64, 0, stream>>>(stats, stats + 2 * DD, gamma, beta);
    k_final  <<<NN * DD / 4 / 256, 256, 0, stream>>>(out, stats + 2 * DD);
}

// Round 4
// 458.800 us; speedup vs baseline: 3.3958x; 1.1157x over previous
//
#include <hip/hip_runtime.h>
#include <hip/hip_bf16.h>

#define NN 100000
#define NE 1600000
#define DD 64
#define NBLK 98          // ceil(NN / 1024)
#define GEMM_BLOCKS (NN / 16)   // 6250
#define HIST_BLOCKS (NE / 256)  // 6250

// ---------------- K1: fused  support = x@W  (blocks [0,6250))  +  dst histogram (blocks [6250,12500)) ----------------
__global__ __launch_bounds__(256) void k_gemm_hist(const float* __restrict__ x,
                                                   const float* __restrict__ Wg,
                                                   float* __restrict__ support,
                                                   const int* __restrict__ edst,
                                                   int* __restrict__ cnt) {
    __shared__ float Ws[DD * DD];
    if (blockIdx.x >= GEMM_BLOCKS) {
        const int e = (blockIdx.x - GEMM_BLOCKS) * 256 + threadIdx.x;
        atomicAdd(&cnt[edst[e]], 1);
        return;
    }
    for (int i = threadIdx.x; i < DD * DD; i += 256)
        Ws[i] = Wg[i];
    __syncthreads();

    const int wave = threadIdx.x >> 6, lane = threadIdx.x & 63;
    const size_t row0 = (size_t)blockIdx.x * 16 + (size_t)wave * 4;
    const float* xr = x + row0 * DD;

    float acc0 = 0.f, acc1 = 0.f, acc2 = 0.f, acc3 = 0.f;
#pragma unroll
    for (int k = 0; k < DD; k += 4) {
        float4 p0 = *(const float4*)(xr + 0 * DD + k);
        float4 p1 = *(const float4*)(xr + 1 * DD + k);
        float4 p2 = *(const float4*)(xr + 2 * DD + k);
        float4 p3 = *(const float4*)(xr + 3 * DD + k);
        float w0 = Ws[(k + 0) * DD + lane];
        float w1 = Ws[(k + 1) * DD + lane];
        float w2 = Ws[(k + 2) * DD + lane];
        float w3 = Ws[(k + 3) * DD + lane];
        acc0 = fmaf(p0.x, w0, acc0); acc0 = fmaf(p0.y, w1, acc0);
        acc0 = fmaf(p0.z, w2, acc0); acc0 = fmaf(p0.w, w3, acc0);
        acc1 = fmaf(p1.x, w0, acc1); acc1 = fmaf(p1.y, w1, acc1);
        acc1 = fmaf(p1.z, w2, acc1); acc1 = fmaf(p1.w, w3, acc1);
        acc2 = fmaf(p2.x, w0, acc2); acc2 = fmaf(p2.y, w1, acc2);
        acc2 = fmaf(p2.z, w2, acc2); acc2 = fmaf(p2.w, w3, acc2);
        acc3 = fmaf(p3.x, w0, acc3); acc3 = fmaf(p3.y, w1, acc3);
        acc3 = fmaf(p3.z, w2, acc3); acc3 = fmaf(p3.w, w3, acc3);
    }
    float* sp = support + row0 * DD + lane;
    sp[0 * DD] = acc0; sp[1 * DD] = acc1; sp[2 * DD] = acc2; sp[3 * DD] = acc3;
}

// ---------------- K2: chunk sums (1024-wide) + exclusive scan of chunk sums, one block ----------------
__global__ __launch_bounds__(1024) void k_bscan(const int* __restrict__ cnt,
                                                int* __restrict__ boff) {
    __shared__ int csum[NBLK];
    const int wave = threadIdx.x >> 6, lane = threadIdx.x & 63;
    for (int c = wave; c < NBLK; c += 16) {
        int s = 0;
#pragma unroll
        for (int k = 0; k < 16; ++k) {
            int i = c * 1024 + lane + 64 * k;
            s += (i < NN) ? cnt[i] : 0;
        }
#pragma unroll
        for (int o = 32; o; o >>= 1) s += __shfl_down(s, o, 64);
        if (lane == 0) csum[c] = s;
    }
    __syncthreads();
    if (threadIdx.x == 0) {
        int run = 0;
        for (int c = 0; c < NBLK; ++c) { int v = csum[c]; boff[c] = run; run += v; }
    }
}

// ---------------- K3: per-chunk exclusive scan + global offset; writes offs[] and cur[] ----------------
__global__ __launch_bounds__(256) void k_scan(const int* __restrict__ cnt,
                                              const int* __restrict__ boff,
                                              int* __restrict__ offs,
                                              int* __restrict__ cur) {
    const int t = threadIdx.x;
    const int base = blockIdx.x * 1024 + t * 4;
    int c[4], ts = 0;
#pragma unroll
    for (int j = 0; j < 4; ++j) {
        int i = base + j;
        c[j] = (i < NN) ? cnt[i] : 0;
        ts += c[j];
    }
    __shared__ int sc[256];
    sc[t] = ts; __syncthreads();
    for (int o = 1; o < 256; o <<= 1) {
        int u = (t >= o) ? sc[t - o] : 0;
        __syncthreads();
        sc[t] += u;
        __syncthreads();
    }
    int run = sc[t] - ts + boff[blockIdx.x];
#pragma unroll
    for (int j = 0; j < 4; ++j) {
        int i = base + j;
        if (i < NN) { offs[i] = run; cur[i] = run; run += c[j]; }
    }
    if (blockIdx.x == 0 && t == 0) offs[NN] = NE;
}

// ---------------- K4: ticket-scatter edges, packed (src, weight) in ONE 8B store ----------------
__global__ __launch_bounds__(256) void k_escat(const int* __restrict__ esrc,
                                               const int* __restrict__ edst,
                                               const float* __restrict__ ew,
                                               int* __restrict__ cur,
                                               int2* __restrict__ perm) {
    const int e = blockIdx.x * 256 + threadIdx.x;   // grid = NE/256 exactly
    const int d = edst[e];
    const int s = esrc[e];
    const float w = ew[e];
    const int p = atomicAdd(&cur[d], 1);
    perm[p] = make_int2(s, __float_as_int(w));
}

// ---------------- K5: gather  agg[d] = sum_e w_e * support[src_e] ----------------
// one wave per dst node; lane = feature; edge metadata via wave-uniform 16B loads
__global__ __launch_bounds__(256) void k_gather(const int* __restrict__ offs,
                                                const int2* __restrict__ perm,
                                                const float* __restrict__ support,
                                                float* __restrict__ agg) {
    const int wave = threadIdx.x >> 6, lane = threadIdx.x & 63;
    const int d = blockIdx.x * 4 + wave;            // grid = NN/4 exactly
    int j = offs[d];
    const int e = offs[d + 1];
    float acc0 = 0.f, acc1 = 0.f, acc2 = 0.f, acc3 = 0.f;
    if (j < e && (j & 1)) {                         // align to 16B
        int2 m = perm[j];
        acc0 = fmaf(__int_as_float(m.y), support[(size_t)m.x * DD + lane], acc0);
        ++j;
    }
    for (; j + 3 < e; j += 4) {
        int4 a = *(const int4*)(perm + j);
        int4 b = *(const int4*)(perm + j + 2);
        acc0 = fmaf(__int_as_float(a.y), support[(size_t)a.x * DD + lane], acc0);
        acc1 = fmaf(__int_as_float(a.w), support[(size_t)a.z * DD + lane], acc1);
        acc2 = fmaf(__int_as_float(b.y), support[(size_t)b.x * DD + lane], acc2);
        acc3 = fmaf(__int_as_float(b.w), support[(size_t)b.z * DD + lane], acc3);
    }
    for (; j < e; ++j) {
        int2 m = perm[j];
        acc0 = fmaf(__int_as_float(m.y), support[(size_t)m.x * DD + lane], acc0);
    }
    agg[(size_t)d * DD + lane] = (acc0 + acc1) + (acc2 + acc3);
}

// ---------------- K6: per-column sum & sumsq ----------------
__device__ inline float4 shfl_down4(float4 v, int d) {
    v.x = __shfl_down(v.x, d, 64); v.y = __shfl_down(v.y, d, 64);
    v.z = __shfl_down(v.z, d, 64); v.w = __shfl_down(v.w, d, 64);
    return v;
}
__device__ inline float4 add4(float4 a, float4 b) {
    a.x += b.x; a.y += b.y; a.z += b.z; a.w += b.w; return a;
}

__global__ __launch_bounds__(256) void k_stats(const float* __restrict__ agg,
                                               float* __restrict__ stats) {
    const int lane = threadIdx.x & 63, wave = threadIdx.x >> 6;
    const int q = lane & 15, sub = lane >> 4;
    float4 s = {0, 0, 0, 0}, sq = {0, 0, 0, 0};
    const int stride = gridDim.x * 16;
    for (int row = (blockIdx.x * 4 + wave) * 4 + sub; row < NN; row += stride) {
        float4 v = *(const float4*)(agg + (size_t)row * DD + q * 4);
        s.x += v.x; s.y += v.y; s.z += v.z; s.w += v.w;
        sq.x = fmaf(v.x, v.x, sq.x); sq.y = fmaf(v.y, v.y, sq.y);
        sq.z = fmaf(v.z, v.z, sq.z); sq.w = fmaf(v.w, v.w, sq.w);
    }
    s = add4(s, shfl_down4(s, 32));  s = add4(s, shfl_down4(s, 16));
    sq = add4(sq, shfl_down4(sq, 32)); sq = add4(sq, shfl_down4(sq, 16));

    __shared__ float red[2][4][DD];
    if (lane < 16) {
        red[0][wave][q * 4 + 0] = s.x;  red[0][wave][q * 4 + 1] = s.y;
        red[0][wave][q * 4 + 2] = s.z;  red[0][wave][q * 4 + 3] = s.w;
        red[1][wave][q * 4 + 0] = sq.x; red[1][wave][q * 4 + 1] = sq.y;
        red[1][wave][q * 4 + 2] = sq.z; red[1][wave][q * 4 + 3] = sq.w;
    }
    __syncthreads();
    if (threadIdx.x < DD) {
        const int c = threadIdx.x;
        atomicAdd(&stats[c],      red[0][0][c] + red[0][1][c] + red[0][2][c] + red[0][3][c]);
        atomicAdd(&stats[DD + c], red[1][0][c] + red[1][1][c] + red[1][2][c] + red[1][3][c]);
    }
}

// ---------------- K7: fold stats into scale/shift ----------------
__global__ void k_finstats(const float* __restrict__ sums, float* __restrict__ ss,
                           const float* __restrict__ gamma,
                           const float* __restrict__ beta) {
    const int c = threadIdx.x;
    const float invn = 1.0f / NN;
    float mean = sums[c] * invn;
    float var = fmaxf(sums[DD + c] * invn - mean * mean, 0.f);
    float sc = rsqrtf(var + 1e-5f) * gamma[c];
    ss[c] = sc;
    ss[DD + c] = beta[c] - mean * sc;
}

// ---------------- K8: out = relu(out*scale + shift) in-place ----------------
__global__ __launch_bounds__(256) void k_final(float* __restrict__ out,
                                               const float* __restrict__ ss) {
    const size_t idx = ((size_t)blockIdx.x * 256 + threadIdx.x) * 4;
    const int c = (int)(idx & 63);
    float4 v = *(const float4*)(out + idx);
    float4 o;
    o.x = fmaxf(fmaf(v.x, ss[c + 0], ss[DD + c + 0]), 0.f);
    o.y = fmaxf(fmaf(v.y, ss[c + 1], ss[DD + c + 1]), 0.f);
    o.z = fmaxf(fmaf(v.z, ss[c + 2], ss[DD + c + 2]), 0.f);
    o.w = fmaxf(fmaf(v.w, ss[c + 3], ss[DD + c + 3]), 0.f);
    *(float4*)(out + idx) = o;
}

extern "C" void kernel_launch(void* const* d_in, const int* in_sizes, int n_in,
                              void* d_out, int out_size, void* d_ws, size_t ws_size,
                              hipStream_t stream) {
    const float* x     = (const float*)d_in[0];
    const int*   esrc  = (const int*)d_in[1];
    const int*   edst  = (const int*)d_in[2];
    const float* ew    = (const float*)d_in[3];
    const float* W     = (const float*)d_in[4];
    // d_in[5] = bias: cancels exactly in batchnorm (shift-invariant) — unused.
    const float* gamma = (const float*)d_in[6];
    const float* beta  = (const float*)d_in[7];
    float*       out   = (float*)d_out;   // doubles as the agg buffer

    // workspace layout (~40 MB)
    char* ws = (char*)d_ws;
    float* support = (float*)ws;   ws += (size_t)NN * DD * 4;  // 25.6 MB
    int2*  perm    = (int2*)ws;    ws += (size_t)NE * 8;       // 12.8 MB (packed src+weight)
    int*   offs    = (int*)ws;     ws += (NN + 4) * 4;
    int*   cur     = (int*)ws;     ws += NN * 4;
    int*   cnt     = (int*)ws;     ws += NN * 4;
    float* stats   = (float*)ws;   ws += 256 * 4;              // sum|sumsq|scale|shift
    int*   boff    = (int*)ws;

    // zero cnt + stats (adjacent); everything else is fully overwritten
    hipMemsetAsync(cnt, 0, (size_t)NN * 4 + 256 * 4, stream);

    k_gemm_hist<<<GEMM_BLOCKS + HIST_BLOCKS, 256, 0, stream>>>(x, W, support, edst, cnt);
    k_bscan    <<<1, 1024, 0, stream>>>(cnt, boff);
    k_scan     <<<NBLK, 256, 0, stream>>>(cnt, boff, offs, cur);
    k_escat    <<<NE / 256, 256, 0, stream>>>(esrc, edst, ew, cur, perm);
    k_gather   <<<NN / 4, 256, 0, stream>>>(offs, perm, support, out);
    k_stats    <<<2048, 256, 0, stream>>>(out, stats);
    k_finstats <<<1, 64, 0, stream>>>(stats, stats + 2 * DD, gamma, beta);
    k_final    <<<NN * DD / 4 / 256, 256, 0, stream>>>(out, stats + 2 * DD);
}